// Round 5
// baseline (364.929 us; speedup 1.0000x reference)
//
#include <hip/hip_runtime.h>

// ---------------------------------------------------------------------------
// Encoder layer on MI355X (gfx950). bf16 MFMA GEMMs + fp32 LN/softmax.
// B=4, S=2048, D=512, F=2048.
// Round 5: 256x256/BK=64 8-wave 8-phase GEMM (m201 template): counted
// vmcnt(6), raw s_barrier, setprio around MFMA, K-chunk XOR swizzle
// (both-sides), staging 1.5 K-tiles ahead into phase-dead LDS regions.
// Split-K=4 for PV/FFN2 (256 blocks each), LN sums 4 partials.
// ---------------------------------------------------------------------------

typedef __attribute__((ext_vector_type(8))) short short8;
typedef __attribute__((ext_vector_type(4))) float f32x4;

#define BARRIER()   asm volatile("s_barrier" ::: "memory")
#define WAITVM(N)   asm volatile("s_waitcnt vmcnt(" #N ")" ::: "memory")
#define WAITLGKM0() asm volatile("s_waitcnt lgkmcnt(0)" ::: "memory")

__device__ __forceinline__ unsigned short f2bf(float f) {
    unsigned int u = __float_as_uint(f);
    unsigned int r = (u + 0x7FFFu + ((u >> 16) & 1u)) >> 16;
    return (unsigned short)r;
}

__device__ __forceinline__ void gload_lds16(const void* g, void* l) {
    __builtin_amdgcn_global_load_lds(
        (const __attribute__((address_space(1))) void*)g,
        (__attribute__((address_space(3))) void*)l, 16, 0, 0);
}

// ---------------------------------------------------------------------------
__global__ __launch_bounds__(256) void cast_f32_bf16(
    const float* __restrict__ in, unsigned short* __restrict__ out, long n4) {
    long i = (long)blockIdx.x * blockDim.x + threadIdx.x;
    if (i < n4) {
        float4 v = ((const float4*)in)[i];
        ushort4 o;
        o.x = f2bf(v.x); o.y = f2bf(v.y); o.z = f2bf(v.z); o.w = f2bf(v.w);
        ((ushort4*)out)[i] = o;
    }
}

__global__ __launch_bounds__(256) void concat3(
    const float* __restrict__ a, const float* __restrict__ b,
    const float* __restrict__ c, float* __restrict__ o, int n) {
    int i = blockIdx.x * blockDim.x + threadIdx.x;
    if (i < n) o[i] = a[i];
    else if (i < 2 * n) o[i] = b[i - n];
    else if (i < 3 * n) o[i] = c[i - 2 * n];
}

// ---------------------------------------------------------------------------
__global__ __launch_bounds__(256) void transpose_cast_f32_bf16(
    const float* __restrict__ in, unsigned short* __restrict__ out, int R, int C) {
    __shared__ float t[32][33];
    int c0 = blockIdx.x * 32, r0 = blockIdx.y * 32;
    int x = threadIdx.x;
    for (int i = threadIdx.y; i < 32; i += 8)
        t[i][x] = in[(long)(r0 + i) * C + c0 + x];
    __syncthreads();
    for (int i = threadIdx.y; i < 32; i += 8)
        out[(long)(c0 + i) * R + r0 + x] = f2bf(t[x][i]);
}

__global__ __launch_bounds__(256) void transpose_bf16(
    const unsigned short* __restrict__ in, unsigned short* __restrict__ out,
    int R, int C, int inLd, long inBatch, long outBatch) {
    __shared__ unsigned short t[32][33];
    long z = blockIdx.z;
    in += z * inBatch; out += z * outBatch;
    int c0 = blockIdx.x * 32, r0 = blockIdx.y * 32;
    int x = threadIdx.x;
    for (int i = threadIdx.y; i < 32; i += 8)
        t[i][x] = in[(long)(r0 + i) * inLd + c0 + x];
    __syncthreads();
    for (int i = threadIdx.y; i < 32; i += 8)
        out[(long)(c0 + i) * R + r0 + x] = t[x][i];
}

// ---------------------------------------------------------------------------
// 256x256 tile, BK=64, 512 threads = 8 waves (2M x 4N), wave tile 128x64.
// Per K-tile: 4 phases; phase q computes M-frag pair {2q,2q+1} x all 4 N-frags
// x K=64 (16 MFMA). B-frags (8) read once at P1, A-frag pair per phase.
// Staging: 8 chunks/K-tile (4 A + 4 B, 64 rows each, one gload_lds per wave),
// 2 per phase, targeting regions dead since the previous phase barrier:
//   P1(t): A1,A3 of t+1   (A rows 64-127/192-255 of buf (t+1)&1, dead P4(t-1))
//   P2(t): B0,B1 of t+2   (B of buf t&1, dead after P1(t))
//   P3(t): B2,B3 of t+2
//   P4(t): A0,A2 of t+2   (A rows 0-63/128-191, dead after P2(t))
// vmcnt(6) once per K-tile at end-P4 (leaves t+2's 6 chunks in flight);
// epilogue drains 2 -> 0. LDS K-chunk swizzle chunk^=(row&7), applied on the
// pre-swizzled GLOBAL source (linear gload dest) and on the ds_read address.
// ---------------------------------------------------------------------------
template<int BIAS, int RELU, int OUT_BF16>
__global__ __launch_bounds__(512, 2) void gemm256(
    const unsigned short* __restrict__ A, const unsigned short* __restrict__ BT,
    const float* __restrict__ bias, void* __restrict__ C,
    int K, int lda, int ldb, int ldc,
    long aBatch, long bBatch, long cBatch,
    long aKOff, long bKOff, long cKOff, int zDiv,
    long aGroup, float scale) {
    __shared__ __align__(16) unsigned short As[2][16384]; // [256][64] x2
    __shared__ __align__(16) unsigned short Bs[2][16384];
    const int tid  = threadIdx.x;
    const int wave = tid >> 6;
    const int lane = tid & 63;
    const int wm = wave >> 2;           // 0..1
    const int wn = wave & 3;            // 0..3
    const int z = blockIdx.z;
    const int b = z / zDiv;
    const int kc = z - b * zDiv;
    const int row0 = blockIdx.y * 256;
    const int col0 = blockIdx.x * 256;
    A  += (long)b * aBatch + (long)kc * aKOff + (long)(col0 >> 9) * aGroup
        + (long)row0 * lda;
    BT += (long)b * bBatch + (long)kc * bKOff + (long)col0 * ldb;
    const long cOff = (long)b * cBatch + (long)kc * cKOff;

    f32x4 acc[8][4] = {};

    // --- staging addressing (per-thread). chunk = 64 rows x 64 cols bf16.
    const int sr = tid >> 3;                      // row within chunk 0..63
    const int sc = (tid & 7) ^ (sr & 7);          // pre-swizzled source K-chunk
    const long aSrcOff = (long)sr * lda + sc * 8;
    const long bSrcOff = (long)sr * ldb + sc * 8;
    const int ldst = wave << 9;                   // wave-uniform dest offset
    const int nt = K >> 6;

    // --- frag-read addressing. row&7 == rA&7 for all frags (16|frag stride).
    const int rA = lane & 15, l4 = lane >> 4;
    const int cp0 = ((l4)     ^ (rA & 7)) << 3;   // ks=0 swizzled chunk offset
    const int cp1 = ((4 + l4) ^ (rA & 7)) << 3;   // ks=1

#define STAGE_A(t, a) gload_lds16(A  + (long)(t) * 64 + (long)(a) * 64 * lda + aSrcOff, \
                                  &As[(t) & 1][(a) * 4096 + ldst])
#define STAGE_B(t, a) gload_lds16(BT + (long)(t) * 64 + (long)(a) * 64 * ldb + bSrcOff, \
                                  &Bs[(t) & 1][(a) * 4096 + ldst])

    // prologue: tile0 full (8), tile1 B0-3 + A0,A2 (6). vmcnt(6) => t0 landed.
    STAGE_B(0, 0); STAGE_B(0, 1); STAGE_B(0, 2); STAGE_B(0, 3);
    STAGE_A(0, 0); STAGE_A(0, 1); STAGE_A(0, 2); STAGE_A(0, 3);
    STAGE_B(1, 0); STAGE_B(1, 1); STAGE_B(1, 2); STAGE_B(1, 3);
    STAGE_A(1, 0); STAGE_A(1, 2);
    WAITVM(6);
    BARRIER();

    for (int t = 0; t < nt; ++t) {
        const int buf = t & 1;
        short8 bfr[4][2];
        short8 afr[2][2];
        // ---------------- P1: read all B + A frags {0,1}; stage A1,A3(t+1)
        #pragma unroll
        for (int fn = 0; fn < 4; ++fn) {
            const int rb = (wn * 64 + fn * 16 + rA) * 64;
            bfr[fn][0] = *(const short8*)&Bs[buf][rb + cp0];
            bfr[fn][1] = *(const short8*)&Bs[buf][rb + cp1];
        }
        #pragma unroll
        for (int i = 0; i < 2; ++i) {
            const int ra = (wm * 128 + i * 16 + rA) * 64;
            afr[i][0] = *(const short8*)&As[buf][ra + cp0];
            afr[i][1] = *(const short8*)&As[buf][ra + cp1];
        }
        if (t + 1 < nt) { STAGE_A(t + 1, 1); STAGE_A(t + 1, 3); }
        BARRIER();
        WAITLGKM0();
        __builtin_amdgcn_sched_barrier(0);
        __builtin_amdgcn_s_setprio(1);
        #pragma unroll
        for (int ks = 0; ks < 2; ++ks)
            #pragma unroll
            for (int i = 0; i < 2; ++i)
                #pragma unroll
                for (int fn = 0; fn < 4; ++fn)
                    acc[i][fn] = __builtin_amdgcn_mfma_f32_16x16x32_bf16(
                        afr[i][ks], bfr[fn][ks], acc[i][fn], 0, 0, 0);
        __builtin_amdgcn_s_setprio(0);
        BARRIER();
        // ---------------- P2..P4
        #pragma unroll
        for (int q = 1; q < 4; ++q) {
            #pragma unroll
            for (int i = 0; i < 2; ++i) {
                const int ra = (wm * 128 + (2 * q + i) * 16 + rA) * 64;
                afr[i][0] = *(const short8*)&As[buf][ra + cp0];
                afr[i][1] = *(const short8*)&As[buf][ra + cp1];
            }
            if (q == 1 && t + 2 < nt) { STAGE_B(t + 2, 0); STAGE_B(t + 2, 1); }
            if (q == 2 && t + 2 < nt) { STAGE_B(t + 2, 2); STAGE_B(t + 2, 3); }
            if (q == 3 && t + 2 < nt) { STAGE_A(t + 2, 0); STAGE_A(t + 2, 2); }
            BARRIER();
            WAITLGKM0();
            __builtin_amdgcn_sched_barrier(0);
            __builtin_amdgcn_s_setprio(1);
            #pragma unroll
            for (int ks = 0; ks < 2; ++ks)
                #pragma unroll
                for (int i = 0; i < 2; ++i)
                    #pragma unroll
                    for (int fn = 0; fn < 4; ++fn)
                        acc[2 * q + i][fn] = __builtin_amdgcn_mfma_f32_16x16x32_bf16(
                            afr[i][ks], bfr[fn][ks], acc[2 * q + i][fn], 0, 0, 0);
            __builtin_amdgcn_s_setprio(0);
            if (q == 1 && t == nt - 1) { WAITVM(0); }   // A1,A3 for P3 of last tile
            if (q == 3) {
                if (t + 2 < nt)       { WAITVM(6); }    // steady: t+2's 6 in flight
                else if (t + 2 == nt) { WAITVM(2); }    // drain: leave A1,A3(nt-1)
            }
            BARRIER();
        }
    }
#undef STAGE_A
#undef STAGE_B

    // epilogue: C/D layout col=lane&15, row=(lane>>4)*4+j
    const int orow = row0 + wm * 128 + l4 * 4;
    const int ocol = col0 + wn * 64 + rA;
    #pragma unroll
    for (int fn = 0; fn < 4; ++fn) {
        const int cc = ocol + fn * 16;
        float bv = 0.0f;
        if (BIAS) bv = bias[cc];
        #pragma unroll
        for (int fm = 0; fm < 8; ++fm) {
            #pragma unroll
            for (int j = 0; j < 4; ++j) {
                float v = acc[fm][fn][j] * scale + bv;
                if (RELU) v = fmaxf(v, 0.0f);
                long off = cOff + (long)(orow + fm * 16 + j) * ldc + cc;
                if (OUT_BF16) ((unsigned short*)C)[off] = f2bf(v);
                else          ((float*)C)[off] = v;
            }
        }
    }
}

// ---------------------------------------------------------------------------
// softmax over rows of 2048 (scale already applied). fp32 in -> bf16 out.
// ---------------------------------------------------------------------------
__global__ __launch_bounds__(256) void softmax_rows(
    const float* __restrict__ S, unsigned short* __restrict__ P) {
    long row = blockIdx.x;
    const float4* src = (const float4*)(S + row * 2048);
    int tid = threadIdx.x;
    int wave = tid >> 6, lane = tid & 63;
    float4 a = src[tid], b = src[tid + 256];
    float e[8] = { a.x, a.y, a.z, a.w, b.x, b.y, b.z, b.w };
    float m = e[0];
    #pragma unroll
    for (int i = 1; i < 8; ++i) m = fmaxf(m, e[i]);
    #pragma unroll
    for (int o = 32; o > 0; o >>= 1) m = fmaxf(m, __shfl_xor(m, o));
    __shared__ float redm[4], reds[4];
    if (lane == 0) redm[wave] = m;
    __syncthreads();
    m = fmaxf(fmaxf(redm[0], redm[1]), fmaxf(redm[2], redm[3]));
    float s = 0.0f;
    #pragma unroll
    for (int i = 0; i < 8; ++i) { e[i] = __expf(e[i] - m); s += e[i]; }
    #pragma unroll
    for (int o = 32; o > 0; o >>= 1) s += __shfl_xor(s, o);
    if (lane == 0) reds[wave] = s;
    __syncthreads();
    s = reds[0] + reds[1] + reds[2] + reds[3];
    float inv = 1.0f / s;
    ushort4 o0, o1;
    o0.x = f2bf(e[0] * inv); o0.y = f2bf(e[1] * inv);
    o0.z = f2bf(e[2] * inv); o0.w = f2bf(e[3] * inv);
    o1.x = f2bf(e[4] * inv); o1.y = f2bf(e[5] * inv);
    o1.z = f2bf(e[6] * inv); o1.w = f2bf(e[7] * inv);
    ushort4* dst = (ushort4*)(P + row * 2048);
    dst[tid] = o0;
    dst[tid + 256] = o1;
}

// ---------------------------------------------------------------------------
// residual + LayerNorm over rows of 512, summing NPART partial fp32 inputs
// (A0 + i*partOff) + optional column bias. optional dual fp32+bf16 output.
// ---------------------------------------------------------------------------
template<int NPART, int BIASF, int DUAL>
__global__ __launch_bounds__(128) void ln_kernel(
    const float* __restrict__ A0, long partOff, const float* __restrict__ R,
    const float* __restrict__ bias,
    const float* __restrict__ g, const float* __restrict__ be,
    float* __restrict__ out, unsigned short* __restrict__ outbf) {
    long row = blockIdx.x;
    int tid = threadIdx.x;
    int wave = tid >> 6, lane = tid & 63;
    float4 v = ((const float4*)(R + row * 512))[tid];
    #pragma unroll
    for (int p = 0; p < NPART; ++p) {
        float4 vp = ((const float4*)(A0 + p * partOff + row * 512))[tid];
        v.x += vp.x; v.y += vp.y; v.z += vp.z; v.w += vp.w;
    }
    if (BIASF) {
        float4 vb = ((const float4*)bias)[tid];
        v.x += vb.x; v.y += vb.y; v.z += vb.z; v.w += vb.w;
    }
    float s  = v.x + v.y + v.z + v.w;
    float s2 = v.x * v.x + v.y * v.y + v.z * v.z + v.w * v.w;
    #pragma unroll
    for (int o = 32; o > 0; o >>= 1) { s += __shfl_xor(s, o); s2 += __shfl_xor(s2, o); }
    __shared__ float r1[2], r2[2];
    if (lane == 0) { r1[wave] = s; r2[wave] = s2; }
    __syncthreads();
    s = r1[0] + r1[1]; s2 = r2[0] + r2[1];
    float mu = s * (1.0f / 512.0f);
    float var = s2 * (1.0f / 512.0f) - mu * mu;
    float rs = rsqrtf(var + 1e-5f);
    float4 gg = ((const float4*)g)[tid];
    float4 bb = ((const float4*)be)[tid];
    float4 y;
    y.x = (v.x - mu) * rs * gg.x + bb.x;
    y.y = (v.y - mu) * rs * gg.y + bb.y;
    y.z = (v.z - mu) * rs * gg.z + bb.z;
    y.w = (v.w - mu) * rs * gg.w + bb.w;
    ((float4*)(out + row * 512))[tid] = y;
    if (DUAL) {
        ushort4 o;
        o.x = f2bf(y.x); o.y = f2bf(y.y); o.z = f2bf(y.z); o.w = f2bf(y.w);
        ((ushort4*)(outbf + row * 512))[tid] = o;
    }
}

// ---------------------------------------------------------------------------
extern "C" void kernel_launch(void* const* d_in, const int* in_sizes, int n_in,
                              void* d_out, int out_size, void* d_ws, size_t ws_size,
                              hipStream_t stream) {
    const float* q   = (const float*)d_in[0];
    const float* k   = (const float*)d_in[1];
    const float* v   = (const float*)d_in[2];
    const float* x   = (const float*)d_in[3];
    const float* Wq  = (const float*)d_in[4];
    const float* bq  = (const float*)d_in[5];
    const float* Wk  = (const float*)d_in[6];
    const float* bk  = (const float*)d_in[7];
    const float* Wv  = (const float*)d_in[8];
    const float* bv  = (const float*)d_in[9];
    const float* g1  = (const float*)d_in[10];
    const float* be1 = (const float*)d_in[11];
    const float* W1  = (const float*)d_in[12];
    const float* b1  = (const float*)d_in[13];
    const float* W2  = (const float*)d_in[14];
    const float* b2  = (const float*)d_in[15];
    const float* g2  = (const float*)d_in[16];
    const float* be2 = (const float*)d_in[17];
    float* out = (float*)d_out;

    const int B = 4, S = 2048, D = 512, F = 2048;
    const long BS = (long)B * S;             // 8192
    const long SD = (long)S * D;             // 1048576 per batch
    const long SS = (long)S * S;             // 4194304 per batch
    const int N3 = 3 * D;                    // 1536

    char* ws = (char*)d_ws;
    size_t off = 0;
    auto alloc = [&](size_t bytes) -> void* {
        void* p = ws + off;
        off += (bytes + 255) & ~(size_t)255;
        return p;
    };
    // persistent weights
    unsigned short* WqkvT = (unsigned short*)alloc((size_t)N3 * D * 2); // [1536][512]
    unsigned short* W1T   = (unsigned short*)alloc((size_t)D * F * 2);  // [F][D]
    unsigned short* W2T   = (unsigned short*)alloc((size_t)F * D * 2);  // [D][F]
    float* bqkv           = (float*)alloc((size_t)N3 * 4);
    // R1: qkv_in bf16 (q,k,v contiguous) -> later VT
    unsigned short* qkv_in = (unsigned short*)alloc(3 * BS * D * 2);    // 25.2MB
    unsigned short* VT = qkv_in;                                        // 8.4MB
    // R2: QKV bf16 [8192][1536] -> later h_f32 + h_bf
    unsigned short* QKV = (unsigned short*)alloc(BS * (size_t)N3 * 2);  // 25.2MB
    float* h_f32 = (float*)QKV;                                         // 16.8MB
    unsigned short* h_bf = (unsigned short*)((char*)QKV + BS * D * 4);  // 8.4MB
    // R3: Sc fp32 -> later attnP (4x) -> later f2P (4x)
    float* Sc = (float*)alloc((size_t)B * SS * 4);                      // 67MB
    float* attnP = Sc;                                                  // 4 x 16.8MB
    float* f2P   = Sc;                                                  // 4 x 16.8MB
    // R4: Pb bf16 -> later f_bf
    unsigned short* Pb = (unsigned short*)alloc((size_t)B * SS * 2);    // 33.5MB
    unsigned short* f_bf = Pb;                                          // 33.5MB

    const float scale = 0.04419417382415922f;  // 1/sqrt(512)

    // 1. casts q,k,v -> bf16 (contiguous)
    {
        long n4 = BS * D / 4;
        int blocks = (int)((n4 + 255) / 256);
        cast_f32_bf16<<<blocks, 256, 0, stream>>>(q, qkv_in, n4);
        cast_f32_bf16<<<blocks, 256, 0, stream>>>(k, qkv_in + BS * D, n4);
        cast_f32_bf16<<<blocks, 256, 0, stream>>>(v, qkv_in + 2 * BS * D, n4);
    }
    // 2. weight transposes + bias concat
    transpose_cast_f32_bf16<<<dim3(D/32, D/32), dim3(32, 8), 0, stream>>>(Wq, WqkvT, D, D);
    transpose_cast_f32_bf16<<<dim3(D/32, D/32), dim3(32, 8), 0, stream>>>(Wk, WqkvT + (size_t)D * D, D, D);
    transpose_cast_f32_bf16<<<dim3(D/32, D/32), dim3(32, 8), 0, stream>>>(Wv, WqkvT + 2 * (size_t)D * D, D, D);
    transpose_cast_f32_bf16<<<dim3(F/32, D/32), dim3(32, 8), 0, stream>>>(W1, W1T, D, F);
    transpose_cast_f32_bf16<<<dim3(D/32, F/32), dim3(32, 8), 0, stream>>>(W2, W2T, F, D);
    concat3<<<(3 * D + 255) / 256, 256, 0, stream>>>(bq, bk, bv, bqkv, D);
    // 3. fused QKV projection: [8192,1536] bf16, A selected per 512-col group
    gemm256<1,0,1><<<dim3(N3/256, 32, 1), 512, 0, stream>>>(
        qkv_in, WqkvT, bqkv, QKV, D, D, D, N3,
        0, 0, 0, 0, 0, 0, 1, BS * D, 1.0f);
    // 4. V transpose per batch: QKV cols 1024..1535 -> VT[b][512][2048]
    transpose_bf16<<<dim3(D/32, S/32, B), dim3(32, 8), 0, stream>>>(
        QKV + 2 * D, VT, S, D, N3, (long)S * N3, SD);
    // 5. scores: per batch [2048,2048] = scale * Q @ K^T
    gemm256<0,0,0><<<dim3(S/256, S/256, B), 512, 0, stream>>>(
        QKV, QKV + D, nullptr, Sc, D, N3, N3, S,
        (long)S * N3, (long)S * N3, SS, 0, 0, 0, 1, 0, scale);
    // 6. softmax -> P bf16
    softmax_rows<<<(int)BS, 256, 0, stream>>>(Sc, Pb);
    // 7. attn = P @ V, split-K=4: z=(b,kc), partials attnP[kc][b][2048][512]
    gemm256<0,0,0><<<dim3(D/256, S/256, 4 * B), 512, 0, stream>>>(
        Pb, VT, nullptr, attnP, S / 4, S, S, D,
        SS, SD, SD, S / 4, S / 4, BS * D, 4, 0, 1.0f);
    // 8. h = LN(sum attnP + x), dual output
    ln_kernel<4,0,1><<<(int)BS, 128, 0, stream>>>(attnP, BS * D, x, nullptr, g1, be1, h_f32, h_bf);
    // 9. f = relu(h @ W1 + b1): [8192,2048] bf16
    gemm256<1,1,1><<<dim3(F/256, 32, 1), 512, 0, stream>>>(
        h_bf, W1T, b1, f_bf, D, D, D, F,
        0, 0, 0, 0, 0, 0, 1, 0, 1.0f);
    // 10. f2 partials = f @ W2, split-K=4 (b2 folded into LN2)
    gemm256<0,0,0><<<dim3(D/256, 32, 4), 512, 0, stream>>>(
        f_bf, W2T, nullptr, f2P, F / 4, F, F, D,
        0, 0, 0, F / 4, F / 4, BS * D, 4, 0, 1.0f);
    // 11. out = LN(sum f2P + b2 + h)
    ln_kernel<4,1,0><<<(int)BS, 128, 0, stream>>>(f2P, BS * D, h_f32, b2, g2, be2, out, nullptr);
}

// Round 6
// 349.403 us; speedup vs baseline: 1.0444x; 1.0444x over previous
//
#include <hip/hip_runtime.h>

// ---------------------------------------------------------------------------
// Encoder layer on MI355X (gfx950). bf16 MFMA GEMMs + fp32 LN/softmax.
// B=4, S=2048, D=512, F=2048.
// Round 6: no split-K (PV/FFN2 via 128x64-tile 2-phase GEMM, 512 blocks =
// 2/CU); bf16 scores; V-transpose fused into QKV epilogue; merged prep
// kernels (10 dispatches total). Wide GEMMs keep the 256x256 8-phase
// schedule (counted vmcnt, setprio, K-chunk XOR swizzle).
// ---------------------------------------------------------------------------

typedef __attribute__((ext_vector_type(8))) short short8;
typedef __attribute__((ext_vector_type(4))) float f32x4;

#define BARRIER()   asm volatile("s_barrier" ::: "memory")
#define WAITVM(N)   asm volatile("s_waitcnt vmcnt(" #N ")" ::: "memory")
#define WAITLGKM0() asm volatile("s_waitcnt lgkmcnt(0)" ::: "memory")

__device__ __forceinline__ unsigned short f2bf(float f) {
    unsigned int u = __float_as_uint(f);
    unsigned int r = (u + 0x7FFFu + ((u >> 16) & 1u)) >> 16;
    return (unsigned short)r;
}
__device__ __forceinline__ float bf2f(unsigned short u) {
    return __uint_as_float((unsigned int)u << 16);
}

__device__ __forceinline__ void gload_lds16(const void* g, void* l) {
    __builtin_amdgcn_global_load_lds(
        (const __attribute__((address_space(1))) void*)g,
        (__attribute__((address_space(3))) void*)l, 16, 0, 0);
}

// ---------------------------------------------------------------------------
// cast q,k,v fp32 -> bf16 into one contiguous buffer (one dispatch)
// ---------------------------------------------------------------------------
__global__ __launch_bounds__(256) void cast3_f32_bf16(
    const float* __restrict__ q, const float* __restrict__ k,
    const float* __restrict__ v, unsigned short* __restrict__ out, long n4) {
    long i = (long)blockIdx.x * blockDim.x + threadIdx.x;
    if (i >= 3 * n4) return;
    const float* src; long j;
    if (i < n4)          { src = q; j = i; }
    else if (i < 2 * n4) { src = k; j = i - n4; }
    else                 { src = v; j = i - 2 * n4; }
    float4 vv = ((const float4*)src)[j];
    ushort4 o;
    o.x = f2bf(vv.x); o.y = f2bf(vv.y); o.z = f2bf(vv.z); o.w = f2bf(vv.w);
    ((ushort4*)out)[i] = o;
}

// ---------------------------------------------------------------------------
// one dispatch: transpose+cast Wq,Wk,Wv,W1,W2 and concat bq|bk|bv
// block z ranges: [0,768) Wq/Wk/Wv; [768,1792) W1; [1792,2816) W2;
// [2816,2822) bias concat.
// ---------------------------------------------------------------------------
__global__ __launch_bounds__(256) void prep_weights(
    const float* __restrict__ Wq, const float* __restrict__ Wk,
    const float* __restrict__ Wv, const float* __restrict__ W1,
    const float* __restrict__ W2,
    const float* __restrict__ bq, const float* __restrict__ bk,
    const float* __restrict__ bv,
    unsigned short* __restrict__ WqkvT, unsigned short* __restrict__ W1T,
    unsigned short* __restrict__ W2T, float* __restrict__ bqkv) {
    int z = blockIdx.x;
    if (z >= 2816) {
        int i = (z - 2816) * 256 + threadIdx.y * 32 + threadIdx.x;
        float val = (i < 512) ? bq[i] : (i < 1024) ? bk[i - 512] : bv[i - 1024];
        bqkv[i] = val;
        return;
    }
    __shared__ float t[32][33];
    const float* in; unsigned short* out; int R, C, r0, c0;
    if (z < 768) {
        int w = z >> 8, zz = z & 255;
        in = (w == 0) ? Wq : (w == 1) ? Wk : Wv;
        out = WqkvT + (size_t)w * 512 * 512;
        R = 512; C = 512;
        c0 = (zz & 15) * 32; r0 = (zz >> 4) * 32;
    } else if (z < 1792) {
        int zz = z - 768;
        in = W1; out = W1T; R = 512; C = 2048;
        c0 = (zz & 63) * 32; r0 = (zz >> 6) * 32;
    } else {
        int zz = z - 1792;
        in = W2; out = W2T; R = 2048; C = 512;
        c0 = (zz & 15) * 32; r0 = (zz >> 4) * 32;
    }
    int x = threadIdx.x;
    for (int i = threadIdx.y; i < 32; i += 8)
        t[i][x] = in[(long)(r0 + i) * C + c0 + x];
    __syncthreads();
    for (int i = threadIdx.y; i < 32; i += 8)
        out[(long)(c0 + i) * R + r0 + x] = f2bf(t[x][i]);
}

// ---------------------------------------------------------------------------
// 256x256 tile, BK=64, 512 threads = 8 waves (2M x 4N), wave tile 128x64.
// 8-phase schedule: per K-tile 4 phases of {ds_read frags | 2 gload_lds |
// barrier | lgkmcnt(0) | setprio(1) 16 MFMA setprio(0) | barrier}, staging
// 1.5 K-tiles ahead into phase-dead LDS regions, vmcnt(6) once per K-tile.
// K-chunk XOR swizzle both-sides (pre-swizzled global src, swizzled ds_read).
// VTROPT: blocks with col0>=1024 write their output transposed into VT
// (fused V-transpose for the QKV projection).
// ---------------------------------------------------------------------------
template<int BIAS, int RELU, int OUT_BF16, int VTROPT>
__global__ __launch_bounds__(512, 2) void gemm256(
    const unsigned short* __restrict__ A, const unsigned short* __restrict__ BT,
    const float* __restrict__ bias, void* __restrict__ C,
    int K, int lda, int ldb, int ldc,
    long aBatch, long bBatch, long cBatch,
    long aGroup, float scale,
    unsigned short* __restrict__ VT, int vS, long vBatch) {
    __shared__ __align__(16) unsigned short As[2][16384]; // [256][64] x2
    __shared__ __align__(16) unsigned short Bs[2][16384];
    const int tid  = threadIdx.x;
    const int wave = tid >> 6;
    const int lane = tid & 63;
    const int wm = wave >> 2;           // 0..1
    const int wn = wave & 3;            // 0..3
    const int b = blockIdx.z;
    const int row0 = blockIdx.y * 256;
    const int col0 = blockIdx.x * 256;
    A  += (long)b * aBatch + (long)(col0 >> 9) * aGroup + (long)row0 * lda;
    BT += (long)b * bBatch + (long)col0 * ldb;
    const long cOff = (long)b * cBatch;

    f32x4 acc[8][4] = {};

    const int sr = tid >> 3;                      // row within chunk 0..63
    const int sc = (tid & 7) ^ (sr & 7);          // pre-swizzled source K-chunk
    const long aSrcOff = (long)sr * lda + sc * 8;
    const long bSrcOff = (long)sr * ldb + sc * 8;
    const int ldst = wave << 9;
    const int nt = K >> 6;

    const int rA = lane & 15, l4 = lane >> 4;
    const int cp0 = ((l4)     ^ (rA & 7)) << 3;
    const int cp1 = ((4 + l4) ^ (rA & 7)) << 3;

#define STAGE_A(t, a) gload_lds16(A  + (long)(t) * 64 + (long)(a) * 64 * lda + aSrcOff, \
                                  &As[(t) & 1][(a) * 4096 + ldst])
#define STAGE_B(t, a) gload_lds16(BT + (long)(t) * 64 + (long)(a) * 64 * ldb + bSrcOff, \
                                  &Bs[(t) & 1][(a) * 4096 + ldst])

    STAGE_B(0, 0); STAGE_B(0, 1); STAGE_B(0, 2); STAGE_B(0, 3);
    STAGE_A(0, 0); STAGE_A(0, 1); STAGE_A(0, 2); STAGE_A(0, 3);
    STAGE_B(1, 0); STAGE_B(1, 1); STAGE_B(1, 2); STAGE_B(1, 3);
    STAGE_A(1, 0); STAGE_A(1, 2);
    WAITVM(6);
    BARRIER();

    for (int t = 0; t < nt; ++t) {
        const int buf = t & 1;
        short8 bfr[4][2];
        short8 afr[2][2];
        #pragma unroll
        for (int fn = 0; fn < 4; ++fn) {
            const int rb = (wn * 64 + fn * 16 + rA) * 64;
            bfr[fn][0] = *(const short8*)&Bs[buf][rb + cp0];
            bfr[fn][1] = *(const short8*)&Bs[buf][rb + cp1];
        }
        #pragma unroll
        for (int i = 0; i < 2; ++i) {
            const int ra = (wm * 128 + i * 16 + rA) * 64;
            afr[i][0] = *(const short8*)&As[buf][ra + cp0];
            afr[i][1] = *(const short8*)&As[buf][ra + cp1];
        }
        if (t + 1 < nt) { STAGE_A(t + 1, 1); STAGE_A(t + 1, 3); }
        BARRIER();
        WAITLGKM0();
        __builtin_amdgcn_sched_barrier(0);
        __builtin_amdgcn_s_setprio(1);
        #pragma unroll
        for (int ks = 0; ks < 2; ++ks)
            #pragma unroll
            for (int i = 0; i < 2; ++i)
                #pragma unroll
                for (int fn = 0; fn < 4; ++fn)
                    acc[i][fn] = __builtin_amdgcn_mfma_f32_16x16x32_bf16(
                        afr[i][ks], bfr[fn][ks], acc[i][fn], 0, 0, 0);
        __builtin_amdgcn_s_setprio(0);
        BARRIER();
        #pragma unroll
        for (int q = 1; q < 4; ++q) {
            #pragma unroll
            for (int i = 0; i < 2; ++i) {
                const int ra = (wm * 128 + (2 * q + i) * 16 + rA) * 64;
                afr[i][0] = *(const short8*)&As[buf][ra + cp0];
                afr[i][1] = *(const short8*)&As[buf][ra + cp1];
            }
            if (q == 1 && t + 2 < nt) { STAGE_B(t + 2, 0); STAGE_B(t + 2, 1); }
            if (q == 2 && t + 2 < nt) { STAGE_B(t + 2, 2); STAGE_B(t + 2, 3); }
            if (q == 3 && t + 2 < nt) { STAGE_A(t + 2, 0); STAGE_A(t + 2, 2); }
            BARRIER();
            WAITLGKM0();
            __builtin_amdgcn_sched_barrier(0);
            __builtin_amdgcn_s_setprio(1);
            #pragma unroll
            for (int ks = 0; ks < 2; ++ks)
                #pragma unroll
                for (int i = 0; i < 2; ++i)
                    #pragma unroll
                    for (int fn = 0; fn < 4; ++fn)
                        acc[2 * q + i][fn] = __builtin_amdgcn_mfma_f32_16x16x32_bf16(
                            afr[i][ks], bfr[fn][ks], acc[2 * q + i][fn], 0, 0, 0);
            __builtin_amdgcn_s_setprio(0);
            if (q == 1 && t == nt - 1) { WAITVM(0); }
            if (q == 3) {
                if (t + 2 < nt)       { WAITVM(6); }
                else if (t + 2 == nt) { WAITVM(2); }
            }
            BARRIER();
        }
    }
#undef STAGE_A
#undef STAGE_B

    // epilogue: C/D layout col=lane&15, row=(lane>>4)*4+j
    const int orow = row0 + wm * 128 + l4 * 4;
    const int ocol = col0 + wn * 64 + rA;
    if (VTROPT && col0 >= 1024) {
        // fused V-transpose: write VT[b][d][s], d = col-1024, s = seq pos
        const int bb = orow >> 11, s0 = orow & 2047;
        #pragma unroll
        for (int fn = 0; fn < 4; ++fn) {
            const int cc = ocol + fn * 16;
            const int d = cc - 1024;
            float bv = 0.0f;
            if (BIAS) bv = bias[cc];
            #pragma unroll
            for (int fm = 0; fm < 8; ++fm) {
                ushort4 o;
                o.x = f2bf(acc[fm][fn][0] * scale + bv);
                o.y = f2bf(acc[fm][fn][1] * scale + bv);
                o.z = f2bf(acc[fm][fn][2] * scale + bv);
                o.w = f2bf(acc[fm][fn][3] * scale + bv);
                *(ushort4*)(VT + (long)bb * vBatch + (long)d * vS + s0 + fm * 16) = o;
            }
        }
        return;
    }
    #pragma unroll
    for (int fn = 0; fn < 4; ++fn) {
        const int cc = ocol + fn * 16;
        float bv = 0.0f;
        if (BIAS) bv = bias[cc];
        #pragma unroll
        for (int fm = 0; fm < 8; ++fm) {
            #pragma unroll
            for (int j = 0; j < 4; ++j) {
                float v = acc[fm][fn][j] * scale + bv;
                if (RELU) v = fmaxf(v, 0.0f);
                long off = cOff + (long)(orow + fm * 16 + j) * ldc + cc;
                if (OUT_BF16) ((unsigned short*)C)[off] = f2bf(v);
                else          ((float*)C)[off] = v;
            }
        }
    }
}

// ---------------------------------------------------------------------------
// 128xBN-tile 2-phase GEMM (m97 structure + K-quad XOR swizzle), BK=32,
// 256 threads = 4 waves (2M x 2N), wave tile 64x(BN/2). For narrow-N GEMMs
// (N=512) this gives 512 blocks = 2 blocks/CU without split-K; inter-block
// overlap hides the barrier drain.
// ---------------------------------------------------------------------------
template<int BN, int BIAS, int RELU, int OUT_BF16>
__global__ __launch_bounds__(256, 2) void gemm_nt(
    const unsigned short* __restrict__ A, const unsigned short* __restrict__ BT,
    const float* __restrict__ bias, void* __restrict__ C,
    int K, int lda, int ldb, int ldc,
    long aBatch, long bBatch, long cBatch, float scale) {
    constexpr int NF = BN / 32;                    // n-frags per wave
    __shared__ __align__(16) unsigned short As[2][4096];      // [128][32]
    __shared__ __align__(16) unsigned short Bs[2][BN * 32];   // [BN][32]
    const int tid  = threadIdx.x;
    const int wave = tid >> 6;
    const int lane = tid & 63;
    const int z = blockIdx.z;
    A  += (long)z * aBatch;
    BT += (long)z * bBatch;
    const int row0 = blockIdx.y * 128;
    const int col0 = blockIdx.x * BN;
    const int wr = (wave >> 1) * 64;
    const int wc = (wave & 1) * (BN / 2);

    f32x4 acc[4][NF] = {};

    const int fs = ((tid >> 2) & 3) ^ ((tid >> 4) & 3);
    const unsigned short* Ag = A  + (long)(row0 + (tid >> 2)) * lda + (((tid & 3) ^ fs) << 3);
    const unsigned short* Bg = BT + (long)(col0 + (tid >> 2)) * ldb + (((tid & 3) ^ fs) << 3);
    const int sBase = wave * 512;

    const int lr  = lane & 15;
    const int fr  = (lr & 3) ^ ((lr >> 2) & 3);
    const int kq8 = (((lane >> 4) ^ fr) << 3);
    const int nk = K >> 5;

    #pragma unroll
    for (int c = 0; c < 2; ++c)
        gload_lds16(Ag + (long)c * 64 * lda, &As[0][sBase + c * 2048]);
    #pragma unroll
    for (int c = 0; c < BN / 64; ++c)
        gload_lds16(Bg + (long)c * 64 * ldb, &Bs[0][sBase + c * 2048]);
    __syncthreads();

    for (int t = 0; t < nk; ++t) {
        const int cur = t & 1;
        if (t + 1 < nk) {
            const int k0 = (t + 1) << 5;
            #pragma unroll
            for (int c = 0; c < 2; ++c)
                gload_lds16(Ag + (long)c * 64 * lda + k0, &As[cur ^ 1][sBase + c * 2048]);
            #pragma unroll
            for (int c = 0; c < BN / 64; ++c)
                gload_lds16(Bg + (long)c * 64 * ldb + k0, &Bs[cur ^ 1][sBase + c * 2048]);
        }
        short8 af[4], bf[NF];
        #pragma unroll
        for (int m = 0; m < 4; ++m)
            af[m] = *(const short8*)&As[cur][(wr + m * 16 + lr) * 32 + kq8];
        #pragma unroll
        for (int n = 0; n < NF; ++n)
            bf[n] = *(const short8*)&Bs[cur][(wc + n * 16 + lr) * 32 + kq8];
        #pragma unroll
        for (int m = 0; m < 4; ++m)
            #pragma unroll
            for (int n = 0; n < NF; ++n)
                acc[m][n] = __builtin_amdgcn_mfma_f32_16x16x32_bf16(
                    af[m], bf[n], acc[m][n], 0, 0, 0);
        __syncthreads();
    }

    const int orow = row0 + wr + (lane >> 4) * 4;
    const int ocol = col0 + wc + lr;
    #pragma unroll
    for (int n = 0; n < NF; ++n) {
        const int cc = ocol + n * 16;
        float bv = 0.0f;
        if (BIAS) bv = bias[cc];
        #pragma unroll
        for (int m = 0; m < 4; ++m) {
            #pragma unroll
            for (int j = 0; j < 4; ++j) {
                float v = acc[m][n][j] * scale + bv;
                if (RELU) v = fmaxf(v, 0.0f);
                long off = (long)z * cBatch + (long)(orow + m * 16 + j) * ldc + cc;
                if (OUT_BF16) ((unsigned short*)C)[off] = f2bf(v);
                else          ((float*)C)[off] = v;
            }
        }
    }
}

// ---------------------------------------------------------------------------
// softmax over rows of 2048, bf16 in (pre-scaled) -> bf16 out.
// 256 threads/row, one short8 per thread.
// ---------------------------------------------------------------------------
__global__ __launch_bounds__(256) void softmax_rows(
    const unsigned short* __restrict__ S, unsigned short* __restrict__ P) {
    long row = blockIdx.x;
    int tid = threadIdx.x;
    int wave = tid >> 6, lane = tid & 63;
    short8 a = ((const short8*)(S + row * 2048))[tid];
    float e[8];
    #pragma unroll
    for (int i = 0; i < 8; ++i) e[i] = bf2f((unsigned short)a[i]);
    float m = e[0];
    #pragma unroll
    for (int i = 1; i < 8; ++i) m = fmaxf(m, e[i]);
    #pragma unroll
    for (int o = 32; o > 0; o >>= 1) m = fmaxf(m, __shfl_xor(m, o));
    __shared__ float redm[4], reds[4];
    if (lane == 0) redm[wave] = m;
    __syncthreads();
    m = fmaxf(fmaxf(redm[0], redm[1]), fmaxf(redm[2], redm[3]));
    float s = 0.0f;
    #pragma unroll
    for (int i = 0; i < 8; ++i) { e[i] = __expf(e[i] - m); s += e[i]; }
    #pragma unroll
    for (int o = 32; o > 0; o >>= 1) s += __shfl_xor(s, o);
    if (lane == 0) reds[wave] = s;
    __syncthreads();
    s = reds[0] + reds[1] + reds[2] + reds[3];
    float inv = 1.0f / s;
    short8 o;
    #pragma unroll
    for (int i = 0; i < 8; ++i) o[i] = (short)f2bf(e[i] * inv);
    ((short8*)(P + row * 2048))[tid] = o;
}

// ---------------------------------------------------------------------------
// residual + LayerNorm over rows of 512. optional dual fp32+bf16 output.
// ---------------------------------------------------------------------------
template<int DUAL>
__global__ __launch_bounds__(128) void ln_kernel(
    const float* __restrict__ A0, const float* __restrict__ R,
    const float* __restrict__ g, const float* __restrict__ be,
    float* __restrict__ out, unsigned short* __restrict__ outbf) {
    long row = blockIdx.x;
    int tid = threadIdx.x;
    int wave = tid >> 6, lane = tid & 63;
    float4 va = ((const float4*)(A0 + row * 512))[tid];
    float4 vr = ((const float4*)(R + row * 512))[tid];
    float4 v;
    v.x = va.x + vr.x; v.y = va.y + vr.y; v.z = va.z + vr.z; v.w = va.w + vr.w;
    float s  = v.x + v.y + v.z + v.w;
    float s2 = v.x * v.x + v.y * v.y + v.z * v.z + v.w * v.w;
    #pragma unroll
    for (int o = 32; o > 0; o >>= 1) { s += __shfl_xor(s, o); s2 += __shfl_xor(s2, o); }
    __shared__ float r1[2], r2[2];
    if (lane == 0) { r1[wave] = s; r2[wave] = s2; }
    __syncthreads();
    s = r1[0] + r1[1]; s2 = r2[0] + r2[1];
    float mu = s * (1.0f / 512.0f);
    float var = s2 * (1.0f / 512.0f) - mu * mu;
    float rs = rsqrtf(var + 1e-5f);
    float4 gg = ((const float4*)g)[tid];
    float4 bb = ((const float4*)be)[tid];
    float4 y;
    y.x = (v.x - mu) * rs * gg.x + bb.x;
    y.y = (v.y - mu) * rs * gg.y + bb.y;
    y.z = (v.z - mu) * rs * gg.z + bb.z;
    y.w = (v.w - mu) * rs * gg.w + bb.w;
    ((float4*)(out + row * 512))[tid] = y;
    if (DUAL) {
        ushort4 o;
        o.x = f2bf(y.x); o.y = f2bf(y.y); o.z = f2bf(y.z); o.w = f2bf(y.w);
        ((ushort4*)(outbf + row * 512))[tid] = o;
    }
}

// ---------------------------------------------------------------------------
extern "C" void kernel_launch(void* const* d_in, const int* in_sizes, int n_in,
                              void* d_out, int out_size, void* d_ws, size_t ws_size,
                              hipStream_t stream) {
    const float* q   = (const float*)d_in[0];
    const float* k   = (const float*)d_in[1];
    const float* v   = (const float*)d_in[2];
    const float* x   = (const float*)d_in[3];
    const float* Wq  = (const float*)d_in[4];
    const float* bq  = (const float*)d_in[5];
    const float* Wk  = (const float*)d_in[6];
    const float* bk  = (const float*)d_in[7];
    const float* Wv  = (const float*)d_in[8];
    const float* bv  = (const float*)d_in[9];
    const float* g1  = (const float*)d_in[10];
    const float* be1 = (const float*)d_in[11];
    const float* W1  = (const float*)d_in[12];
    const float* b1  = (const float*)d_in[13];
    const float* W2  = (const float*)d_in[14];
    const float* b2  = (const float*)d_in[15];
    const float* g2  = (const float*)d_in[16];
    const float* be2 = (const float*)d_in[17];
    float* out = (float*)d_out;

    const int B = 4, S = 2048, D = 512, F = 2048;
    const long BS = (long)B * S;             // 8192
    const long SD = (long)S * D;             // 1048576 per batch
    const long SS = (long)S * S;             // 4194304 per batch
    const int N3 = 3 * D;                    // 1536

    char* ws = (char*)d_ws;
    size_t off = 0;
    auto alloc = [&](size_t bytes) -> void* {
        void* p = ws + off;
        off += (bytes + 255) & ~(size_t)255;
        return p;
    };
    // persistent weights
    unsigned short* WqkvT = (unsigned short*)alloc((size_t)N3 * D * 2); // [1536][512]
    unsigned short* W1T   = (unsigned short*)alloc((size_t)D * F * 2);  // [F][D]
    unsigned short* W2T   = (unsigned short*)alloc((size_t)F * D * 2);  // [D][F]
    float* bqkv           = (float*)alloc((size_t)N3 * 4);
    // R1: qkv_in bf16 (q,k,v contiguous) -> later attn fp32
    unsigned short* qkv_in = (unsigned short*)alloc(3 * BS * D * 2);    // 25.2MB
    float* attn = (float*)qkv_in;                                       // 16.8MB
    // R2: QKV bf16 [8192][1536] (V third unused) -> later h_f32 + h_bf
    unsigned short* QKV = (unsigned short*)alloc(BS * (size_t)N3 * 2);  // 25.2MB
    float* h_f32 = (float*)QKV;                                         // 16.8MB
    unsigned short* h_bf = (unsigned short*)((char*)QKV + BS * D * 4);  // 8.4MB
    // R3: VT bf16 [b][512][2048]
    unsigned short* VT = (unsigned short*)alloc(BS * D * 2);            // 8.4MB
    // R4: Sc bf16 -> later f_bf (same size)
    unsigned short* Sc = (unsigned short*)alloc((size_t)B * SS * 2);    // 33.5MB
    unsigned short* f_bf = Sc;                                          // 33.5MB
    // R5: Pb bf16 -> later f2 fp32
    unsigned short* Pb = (unsigned short*)alloc((size_t)B * SS * 2);    // 33.5MB
    float* f2 = (float*)Pb;                                             // 16.8MB

    const float scale = 0.04419417382415922f;  // 1/sqrt(512)

    // 1. cast q,k,v -> bf16 (one dispatch)
    {
        long n4 = BS * D / 4;
        cast3_f32_bf16<<<(int)((3 * n4 + 255) / 256), 256, 0, stream>>>(
            q, k, v, qkv_in, n4);
    }
    // 2. weight transposes + bias concat (one dispatch)
    prep_weights<<<2822, dim3(32, 8), 0, stream>>>(
        Wq, Wk, Wv, W1, W2, bq, bk, bv, WqkvT, W1T, W2T, bqkv);
    // 3. fused QKV projection [8192,1536]; V third written transposed to VT
    gemm256<1,0,1,1><<<dim3(N3/256, 32, 1), 512, 0, stream>>>(
        qkv_in, WqkvT, bqkv, QKV, D, D, D, N3,
        0, 0, 0, BS * D, 1.0f, VT, S, SD);
    // 4. scores: per batch [2048,2048] = scale * Q @ K^T -> bf16
    gemm256<0,0,1,0><<<dim3(S/256, S/256, B), 512, 0, stream>>>(
        QKV, QKV + D, nullptr, Sc, D, N3, N3, S,
        (long)S * N3, (long)S * N3, SS, 0, scale, nullptr, 0, 0);
    // 5. softmax -> P bf16
    softmax_rows<<<(int)BS, 256, 0, stream>>>(Sc, Pb);
    // 6. attn = P @ V: per batch [2048,512], 128x64 tiles, 512 blocks
    gemm_nt<64,0,0,0><<<dim3(D/64, S/128, B), 256, 0, stream>>>(
        Pb, VT, nullptr, attn, S, S, S, D, SS, SD, SD, 1.0f);
    // 7. h = LN(attn + x), dual output
    ln_kernel<1><<<(int)BS, 128, 0, stream>>>(attn, x, g1, be1, h_f32, h_bf);
    // 8. f = relu(h @ W1 + b1): [8192,2048] bf16
    gemm256<1,1,1,0><<<dim3(F/256, 32, 1), 512, 0, stream>>>(
        h_bf, W1T, b1, f_bf, D, D, D, F,
        0, 0, 0, 0, 1.0f, nullptr, 0, 0);
    // 9. f2 = f @ W2 + b2: [8192,512] fp32, 128x64 tiles, 512 blocks
    gemm_nt<64,1,0,0><<<dim3(D/64, (int)BS/128, 1), 256, 0, stream>>>(
        f_bf, W2T, b2, f2, F, F, F, D, 0, 0, 0, 1.0f);
    // 10. out = LN(f2 + h)
    ln_kernel<0><<<(int)BS, 128, 0, stream>>>(f2, h_f32, g2, be2, out, nullptr);
}

// Round 7
// 330.076 us; speedup vs baseline: 1.1056x; 1.0586x over previous
//
#include <hip/hip_runtime.h>

// ---------------------------------------------------------------------------
// Encoder layer on MI355X (gfx950). bf16 MFMA GEMMs + fp32 LN/softmax.
// B=4, S=2048, D=512, F=2048.
// Round 7: XCD-aware block swizzle on ALL GEMMs (1D grid; xcd=id&7 owns a
// contiguous band of row-panels across all columns -> per-XCD working set
// ~6MB, L2-resident; fixes the 135MB over-fetch on PV/FFN2). Otherwise
// identical to round 6 (256x256 8-phase wide GEMMs, 128x64 2-phase narrow,
// fused V-transpose, bf16 scores, merged prep).
// ---------------------------------------------------------------------------

typedef __attribute__((ext_vector_type(8))) short short8;
typedef __attribute__((ext_vector_type(4))) float f32x4;

#define BARRIER()   asm volatile("s_barrier" ::: "memory")
#define WAITVM(N)   asm volatile("s_waitcnt vmcnt(" #N ")" ::: "memory")
#define WAITLGKM0() asm volatile("s_waitcnt lgkmcnt(0)" ::: "memory")

__device__ __forceinline__ unsigned short f2bf(float f) {
    unsigned int u = __float_as_uint(f);
    unsigned int r = (u + 0x7FFFu + ((u >> 16) & 1u)) >> 16;
    return (unsigned short)r;
}
__device__ __forceinline__ float bf2f(unsigned short u) {
    return __uint_as_float((unsigned int)u << 16);
}

__device__ __forceinline__ void gload_lds16(const void* g, void* l) {
    __builtin_amdgcn_global_load_lds(
        (const __attribute__((address_space(1))) void*)g,
        (__attribute__((address_space(3))) void*)l, 16, 0, 0);
}

// ---------------------------------------------------------------------------
// cast q,k,v fp32 -> bf16 into one contiguous buffer (one dispatch)
// ---------------------------------------------------------------------------
__global__ __launch_bounds__(256) void cast3_f32_bf16(
    const float* __restrict__ q, const float* __restrict__ k,
    const float* __restrict__ v, unsigned short* __restrict__ out, long n4) {
    long i = (long)blockIdx.x * blockDim.x + threadIdx.x;
    if (i >= 3 * n4) return;
    const float* src; long j;
    if (i < n4)          { src = q; j = i; }
    else if (i < 2 * n4) { src = k; j = i - n4; }
    else                 { src = v; j = i - 2 * n4; }
    float4 vv = ((const float4*)src)[j];
    ushort4 o;
    o.x = f2bf(vv.x); o.y = f2bf(vv.y); o.z = f2bf(vv.z); o.w = f2bf(vv.w);
    ((ushort4*)out)[i] = o;
}

// ---------------------------------------------------------------------------
// one dispatch: transpose+cast Wq,Wk,Wv,W1,W2 and concat bq|bk|bv
// ---------------------------------------------------------------------------
__global__ __launch_bounds__(256) void prep_weights(
    const float* __restrict__ Wq, const float* __restrict__ Wk,
    const float* __restrict__ Wv, const float* __restrict__ W1,
    const float* __restrict__ W2,
    const float* __restrict__ bq, const float* __restrict__ bk,
    const float* __restrict__ bv,
    unsigned short* __restrict__ WqkvT, unsigned short* __restrict__ W1T,
    unsigned short* __restrict__ W2T, float* __restrict__ bqkv) {
    int z = blockIdx.x;
    if (z >= 2816) {
        int i = (z - 2816) * 256 + threadIdx.y * 32 + threadIdx.x;
        float val = (i < 512) ? bq[i] : (i < 1024) ? bk[i - 512] : bv[i - 1024];
        bqkv[i] = val;
        return;
    }
    __shared__ float t[32][33];
    const float* in; unsigned short* out; int R, C, r0, c0;
    if (z < 768) {
        int w = z >> 8, zz = z & 255;
        in = (w == 0) ? Wq : (w == 1) ? Wk : Wv;
        out = WqkvT + (size_t)w * 512 * 512;
        R = 512; C = 512;
        c0 = (zz & 15) * 32; r0 = (zz >> 4) * 32;
    } else if (z < 1792) {
        int zz = z - 768;
        in = W1; out = W1T; R = 512; C = 2048;
        c0 = (zz & 63) * 32; r0 = (zz >> 6) * 32;
    } else {
        int zz = z - 1792;
        in = W2; out = W2T; R = 2048; C = 512;
        c0 = (zz & 15) * 32; r0 = (zz >> 4) * 32;
    }
    int x = threadIdx.x;
    for (int i = threadIdx.y; i < 32; i += 8)
        t[i][x] = in[(long)(r0 + i) * C + c0 + x];
    __syncthreads();
    for (int i = threadIdx.y; i < 32; i += 8)
        out[(long)(c0 + i) * R + r0 + x] = f2bf(t[x][i]);
}

// ---------------------------------------------------------------------------
// XCD-aware decomposition of a 1D grid into (col, row-panel y, batch z):
// hardware assigns blockIdx round-robin to the 8 XCDs, so id&7 = XCD.
// XCD i owns row-panels [i*rpb, (i+1)*rpb) across ALL columns -> per-XCD
// A-band + B-panel stay L2-resident. Requires grid%8==0 and (ny*nz)%8==0.
// ---------------------------------------------------------------------------
__device__ __forceinline__ void xcd_map(int nx, int ny, int rpb,
                                        int& colb, int& yb, int& zb) {
    const int id = blockIdx.x;
    const int xcd = id & 7;
    const int j = id >> 3;
    colb = j % nx;
    const int rp = xcd * rpb + j / nx;
    yb = rp % ny;
    zb = rp / ny;
}

// ---------------------------------------------------------------------------
// 256x256 tile, BK=64, 512 threads = 8 waves (2M x 4N), wave tile 128x64.
// 8-phase schedule, counted vmcnt(6), setprio, K-chunk XOR swizzle.
// VTROPT: blocks with col0>=1024 write output transposed into VT.
// ---------------------------------------------------------------------------
template<int BIAS, int RELU, int OUT_BF16, int VTROPT>
__global__ __launch_bounds__(512, 2) void gemm256(
    const unsigned short* __restrict__ A, const unsigned short* __restrict__ BT,
    const float* __restrict__ bias, void* __restrict__ C,
    int K, int lda, int ldb, int ldc,
    long aBatch, long bBatch, long cBatch,
    long aGroup, float scale,
    unsigned short* __restrict__ VT, int vS, long vBatch,
    int nx, int ny, int rpb) {
    __shared__ __align__(16) unsigned short As[2][16384]; // [256][64] x2
    __shared__ __align__(16) unsigned short Bs[2][16384];
    const int tid  = threadIdx.x;
    const int wave = tid >> 6;
    const int lane = tid & 63;
    const int wm = wave >> 2;           // 0..1
    const int wn = wave & 3;            // 0..3
    int colb, yb, b;
    xcd_map(nx, ny, rpb, colb, yb, b);
    const int row0 = yb * 256;
    const int col0 = colb * 256;
    A  += (long)b * aBatch + (long)(col0 >> 9) * aGroup + (long)row0 * lda;
    BT += (long)b * bBatch + (long)col0 * ldb;
    const long cOff = (long)b * cBatch;

    f32x4 acc[8][4] = {};

    const int sr = tid >> 3;                      // row within chunk 0..63
    const int sc = (tid & 7) ^ (sr & 7);          // pre-swizzled source K-chunk
    const long aSrcOff = (long)sr * lda + sc * 8;
    const long bSrcOff = (long)sr * ldb + sc * 8;
    const int ldst = wave << 9;
    const int nt = K >> 6;

    const int rA = lane & 15, l4 = lane >> 4;
    const int cp0 = ((l4)     ^ (rA & 7)) << 3;
    const int cp1 = ((4 + l4) ^ (rA & 7)) << 3;

#define STAGE_A(t, a) gload_lds16(A  + (long)(t) * 64 + (long)(a) * 64 * lda + aSrcOff, \
                                  &As[(t) & 1][(a) * 4096 + ldst])
#define STAGE_B(t, a) gload_lds16(BT + (long)(t) * 64 + (long)(a) * 64 * ldb + bSrcOff, \
                                  &Bs[(t) & 1][(a) * 4096 + ldst])

    STAGE_B(0, 0); STAGE_B(0, 1); STAGE_B(0, 2); STAGE_B(0, 3);
    STAGE_A(0, 0); STAGE_A(0, 1); STAGE_A(0, 2); STAGE_A(0, 3);
    STAGE_B(1, 0); STAGE_B(1, 1); STAGE_B(1, 2); STAGE_B(1, 3);
    STAGE_A(1, 0); STAGE_A(1, 2);
    WAITVM(6);
    BARRIER();

    for (int t = 0; t < nt; ++t) {
        const int buf = t & 1;
        short8 bfr[4][2];
        short8 afr[2][2];
        #pragma unroll
        for (int fn = 0; fn < 4; ++fn) {
            const int rb = (wn * 64 + fn * 16 + rA) * 64;
            bfr[fn][0] = *(const short8*)&Bs[buf][rb + cp0];
            bfr[fn][1] = *(const short8*)&Bs[buf][rb + cp1];
        }
        #pragma unroll
        for (int i = 0; i < 2; ++i) {
            const int ra = (wm * 128 + i * 16 + rA) * 64;
            afr[i][0] = *(const short8*)&As[buf][ra + cp0];
            afr[i][1] = *(const short8*)&As[buf][ra + cp1];
        }
        if (t + 1 < nt) { STAGE_A(t + 1, 1); STAGE_A(t + 1, 3); }
        BARRIER();
        WAITLGKM0();
        __builtin_amdgcn_sched_barrier(0);
        __builtin_amdgcn_s_setprio(1);
        #pragma unroll
        for (int ks = 0; ks < 2; ++ks)
            #pragma unroll
            for (int i = 0; i < 2; ++i)
                #pragma unroll
                for (int fn = 0; fn < 4; ++fn)
                    acc[i][fn] = __builtin_amdgcn_mfma_f32_16x16x32_bf16(
                        afr[i][ks], bfr[fn][ks], acc[i][fn], 0, 0, 0);
        __builtin_amdgcn_s_setprio(0);
        BARRIER();
        #pragma unroll
        for (int q = 1; q < 4; ++q) {
            #pragma unroll
            for (int i = 0; i < 2; ++i) {
                const int ra = (wm * 128 + (2 * q + i) * 16 + rA) * 64;
                afr[i][0] = *(const short8*)&As[buf][ra + cp0];
                afr[i][1] = *(const short8*)&As[buf][ra + cp1];
            }
            if (q == 1 && t + 2 < nt) { STAGE_B(t + 2, 0); STAGE_B(t + 2, 1); }
            if (q == 2 && t + 2 < nt) { STAGE_B(t + 2, 2); STAGE_B(t + 2, 3); }
            if (q == 3 && t + 2 < nt) { STAGE_A(t + 2, 0); STAGE_A(t + 2, 2); }
            BARRIER();
            WAITLGKM0();
            __builtin_amdgcn_sched_barrier(0);
            __builtin_amdgcn_s_setprio(1);
            #pragma unroll
            for (int ks = 0; ks < 2; ++ks)
                #pragma unroll
                for (int i = 0; i < 2; ++i)
                    #pragma unroll
                    for (int fn = 0; fn < 4; ++fn)
                        acc[2 * q + i][fn] = __builtin_amdgcn_mfma_f32_16x16x32_bf16(
                            afr[i][ks], bfr[fn][ks], acc[2 * q + i][fn], 0, 0, 0);
            __builtin_amdgcn_s_setprio(0);
            if (q == 1 && t == nt - 1) { WAITVM(0); }
            if (q == 3) {
                if (t + 2 < nt)       { WAITVM(6); }
                else if (t + 2 == nt) { WAITVM(2); }
            }
            BARRIER();
        }
    }
#undef STAGE_A
#undef STAGE_B

    // epilogue: C/D layout col=lane&15, row=(lane>>4)*4+j
    const int orow = row0 + wm * 128 + l4 * 4;
    const int ocol = col0 + wn * 64 + rA;
    if (VTROPT && col0 >= 1024) {
        const int bb = orow >> 11, s0 = orow & 2047;
        #pragma unroll
        for (int fn = 0; fn < 4; ++fn) {
            const int cc = ocol + fn * 16;
            const int d = cc - 1024;
            float bv = 0.0f;
            if (BIAS) bv = bias[cc];
            #pragma unroll
            for (int fm = 0; fm < 8; ++fm) {
                ushort4 o;
                o.x = f2bf(acc[fm][fn][0] * scale + bv);
                o.y = f2bf(acc[fm][fn][1] * scale + bv);
                o.z = f2bf(acc[fm][fn][2] * scale + bv);
                o.w = f2bf(acc[fm][fn][3] * scale + bv);
                *(ushort4*)(VT + (long)bb * vBatch + (long)d * vS + s0 + fm * 16) = o;
            }
        }
        return;
    }
    #pragma unroll
    for (int fn = 0; fn < 4; ++fn) {
        const int cc = ocol + fn * 16;
        float bv = 0.0f;
        if (BIAS) bv = bias[cc];
        #pragma unroll
        for (int fm = 0; fm < 8; ++fm) {
            #pragma unroll
            for (int j = 0; j < 4; ++j) {
                float v = acc[fm][fn][j] * scale + bv;
                if (RELU) v = fmaxf(v, 0.0f);
                long off = cOff + (long)(orow + fm * 16 + j) * ldc + cc;
                if (OUT_BF16) ((unsigned short*)C)[off] = f2bf(v);
                else          ((float*)C)[off] = v;
            }
        }
    }
}

// ---------------------------------------------------------------------------
// 128xBN-tile 2-phase GEMM (m97 structure + K-quad XOR swizzle), BK=32,
// 256 threads = 4 waves (2M x 2N), wave tile 64x(BN/2). XCD-swizzled 1D grid.
// ---------------------------------------------------------------------------
template<int BN, int BIAS, int RELU, int OUT_BF16>
__global__ __launch_bounds__(256, 2) void gemm_nt(
    const unsigned short* __restrict__ A, const unsigned short* __restrict__ BT,
    const float* __restrict__ bias, void* __restrict__ C,
    int K, int lda, int ldb, int ldc,
    long aBatch, long bBatch, long cBatch, float scale,
    int nx, int ny, int rpb) {
    constexpr int NF = BN / 32;                    // n-frags per wave
    __shared__ __align__(16) unsigned short As[2][4096];      // [128][32]
    __shared__ __align__(16) unsigned short Bs[2][BN * 32];   // [BN][32]
    const int tid  = threadIdx.x;
    const int wave = tid >> 6;
    const int lane = tid & 63;
    int colb, yb, z;
    xcd_map(nx, ny, rpb, colb, yb, z);
    A  += (long)z * aBatch;
    BT += (long)z * bBatch;
    const int row0 = yb * 128;
    const int col0 = colb * BN;
    const int wr = (wave >> 1) * 64;
    const int wc = (wave & 1) * (BN / 2);

    f32x4 acc[4][NF] = {};

    const int fs = ((tid >> 2) & 3) ^ ((tid >> 4) & 3);
    const unsigned short* Ag = A  + (long)(row0 + (tid >> 2)) * lda + (((tid & 3) ^ fs) << 3);
    const unsigned short* Bg = BT + (long)(col0 + (tid >> 2)) * ldb + (((tid & 3) ^ fs) << 3);
    const int sBase = wave * 512;

    const int lr  = lane & 15;
    const int fr  = (lr & 3) ^ ((lr >> 2) & 3);
    const int kq8 = (((lane >> 4) ^ fr) << 3);
    const int nk = K >> 5;

    #pragma unroll
    for (int c = 0; c < 2; ++c)
        gload_lds16(Ag + (long)c * 64 * lda, &As[0][sBase + c * 2048]);
    #pragma unroll
    for (int c = 0; c < BN / 64; ++c)
        gload_lds16(Bg + (long)c * 64 * ldb, &Bs[0][sBase + c * 2048]);
    __syncthreads();

    for (int t = 0; t < nk; ++t) {
        const int cur = t & 1;
        if (t + 1 < nk) {
            const int k0 = (t + 1) << 5;
            #pragma unroll
            for (int c = 0; c < 2; ++c)
                gload_lds16(Ag + (long)c * 64 * lda + k0, &As[cur ^ 1][sBase + c * 2048]);
            #pragma unroll
            for (int c = 0; c < BN / 64; ++c)
                gload_lds16(Bg + (long)c * 64 * ldb + k0, &Bs[cur ^ 1][sBase + c * 2048]);
        }
        short8 af[4], bf[NF];
        #pragma unroll
        for (int m = 0; m < 4; ++m)
            af[m] = *(const short8*)&As[cur][(wr + m * 16 + lr) * 32 + kq8];
        #pragma unroll
        for (int n = 0; n < NF; ++n)
            bf[n] = *(const short8*)&Bs[cur][(wc + n * 16 + lr) * 32 + kq8];
        #pragma unroll
        for (int m = 0; m < 4; ++m)
            #pragma unroll
            for (int n = 0; n < NF; ++n)
                acc[m][n] = __builtin_amdgcn_mfma_f32_16x16x32_bf16(
                    af[m], bf[n], acc[m][n], 0, 0, 0);
        __syncthreads();
    }

    const int orow = row0 + wr + (lane >> 4) * 4;
    const int ocol = col0 + wc + lr;
    #pragma unroll
    for (int n = 0; n < NF; ++n) {
        const int cc = ocol + n * 16;
        float bv = 0.0f;
        if (BIAS) bv = bias[cc];
        #pragma unroll
        for (int m = 0; m < 4; ++m) {
            #pragma unroll
            for (int j = 0; j < 4; ++j) {
                float v = acc[m][n][j] * scale + bv;
                if (RELU) v = fmaxf(v, 0.0f);
                long off = (long)z * cBatch + (long)(orow + m * 16 + j) * ldc + cc;
                if (OUT_BF16) ((unsigned short*)C)[off] = f2bf(v);
                else          ((float*)C)[off] = v;
            }
        }
    }
}

// ---------------------------------------------------------------------------
// softmax over rows of 2048, bf16 in (pre-scaled) -> bf16 out.
// ---------------------------------------------------------------------------
__global__ __launch_bounds__(256) void softmax_rows(
    const unsigned short* __restrict__ S, unsigned short* __restrict__ P) {
    long row = blockIdx.x;
    int tid = threadIdx.x;
    int wave = tid >> 6, lane = tid & 63;
    short8 a = ((const short8*)(S + row * 2048))[tid];
    float e[8];
    #pragma unroll
    for (int i = 0; i < 8; ++i) e[i] = bf2f((unsigned short)a[i]);
    float m = e[0];
    #pragma unroll
    for (int i = 1; i < 8; ++i) m = fmaxf(m, e[i]);
    #pragma unroll
    for (int o = 32; o > 0; o >>= 1) m = fmaxf(m, __shfl_xor(m, o));
    __shared__ float redm[4], reds[4];
    if (lane == 0) redm[wave] = m;
    __syncthreads();
    m = fmaxf(fmaxf(redm[0], redm[1]), fmaxf(redm[2], redm[3]));
    float s = 0.0f;
    #pragma unroll
    for (int i = 0; i < 8; ++i) { e[i] = __expf(e[i] - m); s += e[i]; }
    #pragma unroll
    for (int o = 32; o > 0; o >>= 1) s += __shfl_xor(s, o);
    if (lane == 0) reds[wave] = s;
    __syncthreads();
    s = reds[0] + reds[1] + reds[2] + reds[3];
    float inv = 1.0f / s;
    short8 o;
    #pragma unroll
    for (int i = 0; i < 8; ++i) o[i] = (short)f2bf(e[i] * inv);
    ((short8*)(P + row * 2048))[tid] = o;
}

// ---------------------------------------------------------------------------
// residual + LayerNorm over rows of 512. optional dual fp32+bf16 output.
// ---------------------------------------------------------------------------
template<int DUAL>
__global__ __launch_bounds__(128) void ln_kernel(
    const float* __restrict__ A0, const float* __restrict__ R,
    const float* __restrict__ g, const float* __restrict__ be,
    float* __restrict__ out, unsigned short* __restrict__ outbf) {
    long row = blockIdx.x;
    int tid = threadIdx.x;
    int wave = tid >> 6, lane = tid & 63;
    float4 va = ((const float4*)(A0 + row * 512))[tid];
    float4 vr = ((const float4*)(R + row * 512))[tid];
    float4 v;
    v.x = va.x + vr.x; v.y = va.y + vr.y; v.z = va.z + vr.z; v.w = va.w + vr.w;
    float s  = v.x + v.y + v.z + v.w;
    float s2 = v.x * v.x + v.y * v.y + v.z * v.z + v.w * v.w;
    #pragma unroll
    for (int o = 32; o > 0; o >>= 1) { s += __shfl_xor(s, o); s2 += __shfl_xor(s2, o); }
    __shared__ float r1[2], r2[2];
    if (lane == 0) { r1[wave] = s; r2[wave] = s2; }
    __syncthreads();
    s = r1[0] + r1[1]; s2 = r2[0] + r2[1];
    float mu = s * (1.0f / 512.0f);
    float var = s2 * (1.0f / 512.0f) - mu * mu;
    float rs = rsqrtf(var + 1e-5f);
    float4 gg = ((const float4*)g)[tid];
    float4 bb = ((const float4*)be)[tid];
    float4 y;
    y.x = (v.x - mu) * rs * gg.x + bb.x;
    y.y = (v.y - mu) * rs * gg.y + bb.y;
    y.z = (v.z - mu) * rs * gg.z + bb.z;
    y.w = (v.w - mu) * rs * gg.w + bb.w;
    ((float4*)(out + row * 512))[tid] = y;
    if (DUAL) {
        ushort4 o;
        o.x = f2bf(y.x); o.y = f2bf(y.y); o.z = f2bf(y.z); o.w = f2bf(y.w);
        ((ushort4*)(outbf + row * 512))[tid] = o;
    }
}

// ---------------------------------------------------------------------------
extern "C" void kernel_launch(void* const* d_in, const int* in_sizes, int n_in,
                              void* d_out, int out_size, void* d_ws, size_t ws_size,
                              hipStream_t stream) {
    const float* q   = (const float*)d_in[0];
    const float* k   = (const float*)d_in[1];
    const float* v   = (const float*)d_in[2];
    const float* x   = (const float*)d_in[3];
    const float* Wq  = (const float*)d_in[4];
    const float* bq  = (const float*)d_in[5];
    const float* Wk  = (const float*)d_in[6];
    const float* bk  = (const float*)d_in[7];
    const float* Wv  = (const float*)d_in[8];
    const float* bv  = (const float*)d_in[9];
    const float* g1  = (const float*)d_in[10];
    const float* be1 = (const float*)d_in[11];
    const float* W1  = (const float*)d_in[12];
    const float* b1  = (const float*)d_in[13];
    const float* W2  = (const float*)d_in[14];
    const float* b2  = (const float*)d_in[15];
    const float* g2  = (const float*)d_in[16];
    const float* be2 = (const float*)d_in[17];
    float* out = (float*)d_out;

    const int B = 4, S = 2048, D = 512, F = 2048;
    const long BS = (long)B * S;             // 8192
    const long SD = (long)S * D;             // 1048576 per batch
    const long SS = (long)S * S;             // 4194304 per batch
    const int N3 = 3 * D;                    // 1536

    char* ws = (char*)d_ws;
    size_t off = 0;
    auto alloc = [&](size_t bytes) -> void* {
        void* p = ws + off;
        off += (bytes + 255) & ~(size_t)255;
        return p;
    };
    // persistent weights
    unsigned short* WqkvT = (unsigned short*)alloc((size_t)N3 * D * 2); // [1536][512]
    unsigned short* W1T   = (unsigned short*)alloc((size_t)D * F * 2);  // [F][D]
    unsigned short* W2T   = (unsigned short*)alloc((size_t)F * D * 2);  // [D][F]
    float* bqkv           = (float*)alloc((size_t)N3 * 4);
    // R1: qkv_in bf16 (q,k,v contiguous) -> later attn fp32
    unsigned short* qkv_in = (unsigned short*)alloc(3 * BS * D * 2);    // 25.2MB
    float* attn = (float*)qkv_in;                                       // 16.8MB
    // R2: QKV bf16 [8192][1536] (V third unused) -> later h_f32 + h_bf
    unsigned short* QKV = (unsigned short*)alloc(BS * (size_t)N3 * 2);  // 25.2MB
    float* h_f32 = (float*)QKV;                                         // 16.8MB
    unsigned short* h_bf = (unsigned short*)((char*)QKV + BS * D * 4);  // 8.4MB
    // R3: VT bf16 [b][512][2048]
    unsigned short* VT = (unsigned short*)alloc(BS * D * 2);            // 8.4MB
    // R4: Sc bf16 -> later f_bf (same size)
    unsigned short* Sc = (unsigned short*)alloc((size_t)B * SS * 2);    // 33.5MB
    unsigned short* f_bf = Sc;                                          // 33.5MB
    // R5: Pb bf16 -> later f2 fp32
    unsigned short* Pb = (unsigned short*)alloc((size_t)B * SS * 2);    // 33.5MB
    float* f2 = (float*)Pb;                                             // 16.8MB

    const float scale = 0.04419417382415922f;  // 1/sqrt(512)

    // 1. cast q,k,v -> bf16 (one dispatch)
    {
        long n4 = BS * D / 4;
        cast3_f32_bf16<<<(int)((3 * n4 + 255) / 256), 256, 0, stream>>>(
            q, k, v, qkv_in, n4);
    }
    // 2. weight transposes + bias concat (one dispatch)
    prep_weights<<<2822, dim3(32, 8), 0, stream>>>(
        Wq, Wk, Wv, W1, W2, bq, bk, bv, WqkvT, W1T, W2T, bqkv);
    // 3. fused QKV projection [8192,1536]; V third written transposed to VT
    //    grid 6x32 -> 192 blocks, rpb = 32/8 = 4
    gemm256<1,0,1,1><<<192, 512, 0, stream>>>(
        qkv_in, WqkvT, bqkv, QKV, D, D, D, N3,
        0, 0, 0, BS * D, 1.0f, VT, S, SD, 6, 32, 4);
    // 4. scores: per batch [2048,2048] = scale * Q @ K^T -> bf16
    //    grid 8x8x4 -> 256 blocks, rpb = 32/8 = 4
    gemm256<0,0,1,0><<<256, 512, 0, stream>>>(
        QKV, QKV + D, nullptr, Sc, D, N3, N3, S,
        (long)S * N3, (long)S * N3, SS, 0, scale, nullptr, 0, 0, 8, 8, 4);
    // 5. softmax -> P bf16
    softmax_rows<<<(int)BS, 256, 0, stream>>>(Sc, Pb);
    // 6. attn = P @ V: per batch [2048,512], 128x64 tiles
    //    grid 8x16x4 -> 512 blocks, rpb = 64/8 = 8
    gemm_nt<64,0,0,0><<<512, 256, 0, stream>>>(
        Pb, VT, nullptr, attn, S, S, S, D, SS, SD, SD, 1.0f, 8, 16, 8);
    // 7. h = LN(attn + x), dual output
    ln_kernel<1><<<(int)BS, 128, 0, stream>>>(attn, x, g1, be1, h_f32, h_bf);
    // 8. f = relu(h @ W1 + b1): [8192,2048] bf16
    //    grid 8x32 -> 256 blocks, rpb = 4
    gemm256<1,1,1,0><<<256, 512, 0, stream>>>(
        h_bf, W1T, b1, f_bf, D, D, D, F,
        0, 0, 0, 0, 1.0f, nullptr, 0, 0, 8, 32, 4);
    // 9. f2 = f @ W2 + b2: [8192,512] fp32, 128x64 tiles
    //    grid 8x64 -> 512 blocks, rpb = 8
    gemm_nt<64,1,0,0><<<512, 256, 0, stream>>>(
        f_bf, W2T, b2, f2, F, F, F, D, 0, 0, 0, 1.0f, 8, 64, 8);
    // 10. out = LN(f2 + h)
    ln_kernel<0><<<(int)BS, 128, 0, stream>>>(f2, h_f32, g2, be2, out, nullptr);
}